// Round 1
// baseline (313.228 us; speedup 1.0000x reference)
//
#include <hip/hip_runtime.h>

// MultiHeadAttention fwd: out = (ctx @ Wo, attn_weights)
// Strategy: fp16 MFMA (16x16x32) everywhere, fp32 accumulate.
// d_out = [output fp32 16*1024*512][attn_weights fp32 16*8*1024*1024]

typedef _Float16 f16;
typedef _Float16 f16x8 __attribute__((ext_vector_type(8)));
typedef float f32x4 __attribute__((ext_vector_type(4)));

#define DEVINL __device__ __forceinline__

static constexpr int BATCH = 16, SEQ = 1024, DM = 512, NH = 8, DH = 64;

// async global->LDS, 16B per lane. lds base must be wave-uniform; HW adds lane*16.
DEVINL void async16(void* lds, const void* g) {
  __builtin_amdgcn_global_load_lds(
      (const __attribute__((address_space(1))) unsigned int*)g,
      (__attribute__((address_space(3))) unsigned int*)lds, 16, 0, 0);
}

// ---------------- weight fp32[k][n] -> fp16 WT[w][n][k] ----------------
__global__ __launch_bounds__(256) void prep_wt_k(
    const float* __restrict__ Wq, const float* __restrict__ Wk,
    const float* __restrict__ Wv, const float* __restrict__ Wo,
    f16* __restrict__ WT) {
  __shared__ float t[32][33];
  const int w = blockIdx.z;
  const float* src = (w == 0) ? Wq : (w == 1) ? Wk : (w == 2) ? Wv : Wo;
  const int k0 = blockIdx.y * 32, n0 = blockIdx.x * 32;
  const int r0 = threadIdx.x >> 5, c = threadIdx.x & 31;
#pragma unroll
  for (int i = 0; i < 4; ++i)
    t[i * 8 + r0][c] = src[(size_t)(k0 + i * 8 + r0) * DM + n0 + c];
  __syncthreads();
  f16* dst = WT + (size_t)w * DM * DM;
#pragma unroll
  for (int i = 0; i < 4; ++i)
    dst[(size_t)(n0 + i * 8 + r0) * DM + k0 + c] = (f16)t[c][i * 8 + r0];
}

// ---------------- 128x128x(K=512) MFMA GEMM body ----------------
// MODE 0: A = fp32 [16384][512] input, convert->fp16; out = fp16 head-split Qh/Kh/Vh
// MODE 1: A = fp16 ctx [16384][512] (async staged); out = fp32 linear [16384][512]
template <int MODE>
DEVINL void gemm_body(const float* __restrict__ A32, const f16* __restrict__ A16,
                      const f16* __restrict__ WTn, f16* __restrict__ O16,
                      float* __restrict__ O32) {
  __shared__ __align__(16) f16 As[128 * 32];
  __shared__ __align__(16) f16 Bs[128 * 32];
  const int tid = threadIdx.x;
  const int lane = tid & 63, wave = tid >> 6;
  const int wr = wave >> 1, wc = wave & 1;
  const int m0 = blockIdx.x * 128, n0 = blockIdx.y * 128;
  const int lrow = lane & 15, lkg = lane >> 4;
  f32x4 acc[4][4] = {};

  for (int kt = 0; kt < DM / 32; ++kt) {
    const int k0 = kt * 32;
    // stage B [128 n][32 k] fp16 via async (linear LDS, linear source rows)
#pragma unroll
    for (int it = 0; it < 2; ++it) {
      const int o = (it * 256 + tid) * 16;
      const int n = o >> 6, kb = o & 63;
      async16((char*)Bs + (it * 256 + wave * 64) * 16,
              (const char*)WTn + ((size_t)(n0 + n) * DM + k0) * 2 + kb);
    }
    // stage A [128 m][32 k]
    if (MODE == 0) {
      const int row = tid >> 1, kh = (tid & 1) * 16;
      const float* s = A32 + (size_t)(m0 + row) * DM + k0 + kh;
#pragma unroll
      for (int half = 0; half < 2; ++half) {
        f32x4 v0 = *(const f32x4*)(s + half * 8);
        f32x4 v1 = *(const f32x4*)(s + half * 8 + 4);
        f16x8 t;
        t[0] = (f16)v0[0]; t[1] = (f16)v0[1]; t[2] = (f16)v0[2]; t[3] = (f16)v0[3];
        t[4] = (f16)v1[0]; t[5] = (f16)v1[1]; t[6] = (f16)v1[2]; t[7] = (f16)v1[3];
        *(f16x8*)&As[row * 32 + kh + half * 8] = t;
      }
    } else {
#pragma unroll
      for (int it = 0; it < 2; ++it) {
        const int o = (it * 256 + tid) * 16;
        const int row = o >> 6, kb = o & 63;
        async16((char*)As + (it * 256 + wave * 64) * 16,
                (const char*)A16 + ((size_t)(m0 + row) * DM + k0) * 2 + kb);
      }
    }
    __syncthreads();
    f16x8 af[4], bf[4];
#pragma unroll
    for (int i = 0; i < 4; ++i)
      af[i] = *(const f16x8*)&As[(wr * 64 + i * 16 + lrow) * 32 + lkg * 8];
#pragma unroll
    for (int j = 0; j < 4; ++j)
      bf[j] = *(const f16x8*)&Bs[(wc * 64 + j * 16 + lrow) * 32 + lkg * 8];
#pragma unroll
    for (int i = 0; i < 4; ++i)
#pragma unroll
      for (int j = 0; j < 4; ++j)
        acc[i][j] = __builtin_amdgcn_mfma_f32_16x16x32_f16(af[i], bf[j], acc[i][j], 0, 0, 0);
    __syncthreads();
  }

  // epilogue. C/D layout: col = lane&15, row = (lane>>4)*4 + reg
#pragma unroll
  for (int i = 0; i < 4; ++i) {
#pragma unroll
    for (int j = 0; j < 4; ++j) {
#pragma unroll
      for (int r = 0; r < 4; ++r) {
        const int m = m0 + wr * 64 + i * 16 + lkg * 4 + r;
        const int g = n0 + wc * 64 + j * 16 + lrow;
        if (MODE == 0) {
          const int b = m >> 10, s = m & 1023, hh = g >> 6, d = g & 63;
          O16[(((size_t)b * NH + hh) * SEQ + s) * DH + d] = (f16)acc[i][j][r];
        } else {
          O32[(size_t)m * DM + g] = acc[i][j][r];
        }
      }
    }
  }
}

__global__ __launch_bounds__(256, 2) void proj_k(
    const float* __restrict__ q, const float* __restrict__ k, const float* __restrict__ v,
    const f16* __restrict__ WT, f16* __restrict__ Qh, f16* __restrict__ Kh,
    f16* __restrict__ Vh) {
  const int z = blockIdx.z;
  const float* A = (z == 0) ? q : (z == 1) ? k : v;
  const f16* W = WT + (size_t)z * DM * DM;
  f16* O = (z == 0) ? Qh : (z == 1) ? Kh : Vh;
  gemm_body<0>(A, nullptr, W, O, nullptr);
}

__global__ __launch_bounds__(256, 2) void outp_k(const f16* __restrict__ ctx,
                                                 const f16* __restrict__ WoT,
                                                 float* __restrict__ out0) {
  gemm_body<1>(nullptr, ctx, WoT, nullptr, out0);
}

// ---------------- attention ----------------
// block = 4 waves, 64 q-rows (wave w owns rows q0 = qt*64 + w*16 .. +15).
// Pass 1: softmax denominators (no max-sub: |logit| << 80, fp32 exp exact).
// Pass 2: recompute QK^T, write normalized weights, PV accumulate.
// LDS rows are 128B -> XOR-swizzle 16B slots with (row&7) to break 16-way conflicts.
__global__ __launch_bounds__(256, 2) void attn_k(
    const f16* __restrict__ Qh, const f16* __restrict__ Kh, const f16* __restrict__ Vh,
    const float* __restrict__ mask, float* __restrict__ attnW, f16* __restrict__ ctx) {
  __shared__ __align__(16) f16 Ks[64 * 64];
  __shared__ __align__(16) f16 Vt[64 * 64];
  __shared__ __align__(16) f16 Ps[4][16 * 64];
  const int tid = threadIdx.x;
  const int lane = tid & 63, wave = tid >> 6;
  const int lrow = lane & 15, lkg = lane >> 4;
  const int qt = blockIdx.x, h = blockIdx.y, b = blockIdx.z;
  const size_t bh = (size_t)b * NH + h;
  const f16* Kbase = Kh + bh * SEQ * DH;
  const f16* Vbase = Vh + bh * SEQ * DH;
  const int q0 = qt * 64 + wave * 16;

  // Q fragments held in registers for the whole kernel
  f16x8 aQ0, aQ1;
  {
    const f16* qp = Qh + (bh * SEQ + q0 + lrow) * DH + lkg * 8;
    aQ0 = *(const f16x8*)qp;
    aQ1 = *(const f16x8*)(qp + 32);
  }

  float sums[4] = {0.f, 0.f, 0.f, 0.f};

  for (int kt = 0; kt < 16; ++kt) {
    const char* KtileB = (const char*)(Kbase + (size_t)kt * 64 * DH);
#pragma unroll
    for (int it = 0; it < 2; ++it) {
      const int o = (it * 256 + tid) * 16;
      const int key = o >> 7, slot = (o >> 4) & 7;
      // pre-swizzled global source, linear LDS dest (m201 pattern)
      async16((char*)Ks + (it * 256 + wave * 64) * 16,
              KtileB + key * 128 + ((slot ^ (key & 7)) << 4));
    }
    __syncthreads();
    f32x4 lg[4] = {};
#pragma unroll
    for (int j = 0; j < 4; ++j) {
      const int key = j * 16 + lrow;
      f16x8 b0 = *(const f16x8*)((const char*)Ks + key * 128 + ((lkg ^ (key & 7)) << 4));
      f16x8 b1 = *(const f16x8*)((const char*)Ks + key * 128 + (((4 + lkg) ^ (key & 7)) << 4));
      lg[j] = __builtin_amdgcn_mfma_f32_16x16x32_f16(aQ0, b0, lg[j], 0, 0, 0);
      lg[j] = __builtin_amdgcn_mfma_f32_16x16x32_f16(aQ1, b1, lg[j], 0, 0, 0);
    }
#pragma unroll
    for (int j = 0; j < 4; ++j) {
      const int key = kt * 64 + j * 16 + lrow;
      const float bias = (1.0f - mask[b * SEQ + key]) * (-1e9f);
#pragma unroll
      for (int r = 0; r < 4; ++r) sums[r] += __expf(lg[j][r] * 0.125f + bias);
    }
    __syncthreads();
  }

  // reduce over the 16 lanes of each row-group (xor bits 0..3 only)
#pragma unroll
  for (int r = 0; r < 4; ++r) {
    float s = sums[r];
    s += __shfl_xor(s, 1);
    s += __shfl_xor(s, 2);
    s += __shfl_xor(s, 4);
    s += __shfl_xor(s, 8);
    sums[r] = 1.0f / s;
  }

  f32x4 ctxacc[4] = {};
  float* awBase = attnW + (bh * SEQ + q0) * SEQ;

  for (int kt = 0; kt < 16; ++kt) {
    const char* KtileB = (const char*)(Kbase + (size_t)kt * 64 * DH);
#pragma unroll
    for (int it = 0; it < 2; ++it) {
      const int o = (it * 256 + tid) * 16;
      const int key = o >> 7, slot = (o >> 4) & 7;
      async16((char*)Ks + (it * 256 + wave * 64) * 16,
              KtileB + key * 128 + ((slot ^ (key & 7)) << 4));
    }
    {  // V transpose-stage: Vt[d][key] (swizzled), coalesced 16B global reads
      const int key = tid >> 2, d0 = (tid & 3) * 16;
      const f16* vp = Vbase + ((size_t)kt * 64 + key) * DH + d0;
      f16x8 v0 = *(const f16x8*)vp;
      f16x8 v1 = *(const f16x8*)(vp + 8);
#pragma unroll
      for (int jj = 0; jj < 8; ++jj) {
        const int d = d0 + jj;
        *(f16*)((char*)Vt + d * 128 + (((key >> 3) ^ (d & 7)) << 4) + (key & 7) * 2) = v0[jj];
      }
#pragma unroll
      for (int jj = 0; jj < 8; ++jj) {
        const int d = d0 + 8 + jj;
        *(f16*)((char*)Vt + d * 128 + (((key >> 3) ^ (d & 7)) << 4) + (key & 7) * 2) = v1[jj];
      }
    }
    __syncthreads();
    f32x4 lg[4] = {};
#pragma unroll
    for (int j = 0; j < 4; ++j) {
      const int key = j * 16 + lrow;
      f16x8 b0 = *(const f16x8*)((const char*)Ks + key * 128 + ((lkg ^ (key & 7)) << 4));
      f16x8 b1 = *(const f16x8*)((const char*)Ks + key * 128 + (((4 + lkg) ^ (key & 7)) << 4));
      lg[j] = __builtin_amdgcn_mfma_f32_16x16x32_f16(aQ0, b0, lg[j], 0, 0, 0);
      lg[j] = __builtin_amdgcn_mfma_f32_16x16x32_f16(aQ1, b1, lg[j], 0, 0, 0);
    }
    float* aw = awBase + kt * 64;
#pragma unroll
    for (int j = 0; j < 4; ++j) {
      const int keyc = j * 16 + lrow;
      const float bias = (1.0f - mask[b * SEQ + kt * 64 + keyc]) * (-1e9f);
#pragma unroll
      for (int r = 0; r < 4; ++r) {
        const int row = lkg * 4 + r;
        const float w = __expf(lg[j][r] * 0.125f + bias) * sums[r];
        aw[(size_t)row * SEQ + keyc] = w;
        *(f16*)((char*)&Ps[wave][0] + row * 128 + (((keyc >> 3) ^ (row & 7)) << 4) +
                (keyc & 7) * 2) = (f16)w;
      }
    }
    // PV: ctx[16 rows][64 d] += P[16][64keys] @ V[64keys][64 d]
#pragma unroll
    for (int kk = 0; kk < 2; ++kk) {
      const int kidx = kk * 32 + lkg * 8;
      f16x8 aP = *(const f16x8*)((const char*)&Ps[wave][0] + lrow * 128 +
                                 (((kidx >> 3) ^ (lrow & 7)) << 4));
#pragma unroll
      for (int j2 = 0; j2 < 4; ++j2) {
        const int d = j2 * 16 + lrow;
        f16x8 bV = *(const f16x8*)((const char*)Vt + d * 128 + (((kidx >> 3) ^ (d & 7)) << 4));
        ctxacc[j2] = __builtin_amdgcn_mfma_f32_16x16x32_f16(aP, bV, ctxacc[j2], 0, 0, 0);
      }
    }
    __syncthreads();
  }

  // ctx layout [b][s][h][d]  (== [16384][512] row-major for the output GEMM)
#pragma unroll
  for (int j2 = 0; j2 < 4; ++j2)
#pragma unroll
    for (int r = 0; r < 4; ++r) {
      const int s = q0 + lkg * 4 + r;
      const int d = j2 * 16 + lrow;
      ctx[(((size_t)b * SEQ + s) * NH + h) * DH + d] = (f16)ctxacc[j2][r];
    }
}

extern "C" void kernel_launch(void* const* d_in, const int* in_sizes, int n_in,
                              void* d_out, int out_size, void* d_ws, size_t ws_size,
                              hipStream_t stream) {
  const float* v = (const float*)d_in[0];
  const float* k = (const float*)d_in[1];
  const float* q = (const float*)d_in[2];
  const float* mask = (const float*)d_in[3];
  const float* Wq = (const float*)d_in[4];
  const float* Wk = (const float*)d_in[5];
  const float* Wv = (const float*)d_in[6];
  const float* Wo = (const float*)d_in[7];

  float* out0 = (float*)d_out;
  float* attnW = out0 + (size_t)BATCH * SEQ * DM;

  char* ws = (char*)d_ws;
  f16* WT = (f16*)ws;                                   // 4*512*512 fp16 = 2 MB
  f16* Qh = (f16*)(ws + (size_t)4 * DM * DM * 2);       // 16.78 MB each
  f16* Kh = Qh + (size_t)BATCH * NH * SEQ * DH;
  f16* Vh = Kh + (size_t)BATCH * NH * SEQ * DH;
  f16* ctx = Vh + (size_t)BATCH * NH * SEQ * DH;

  prep_wt_k<<<dim3(16, 16, 4), 256, 0, stream>>>(Wq, Wk, Wv, Wo, WT);
  proj_k<<<dim3(128, 4, 3), 256, 0, stream>>>(q, k, v, WT, Qh, Kh, Vh);
  attn_k<<<dim3(16, NH, BATCH), 256, 0, stream>>>(Qh, Kh, Vh, mask, attnW, ctx);
  outp_k<<<dim3(128, 4), 256, 0, stream>>>(ctx, WT + (size_t)3 * DM * DM, out0);
}